// Round 5
// baseline (438.500 us; speedup 1.0000x reference)
//
#include <hip/hip_runtime.h>

typedef __attribute__((ext_vector_type(8))) __bf16 bf16x8;
typedef __attribute__((ext_vector_type(4))) float f32x4;

__device__ __forceinline__ unsigned short f2bf(float x) {
  union { float f; unsigned int u; } v; v.f = x;
  unsigned int r = v.u + 0x7fffu + ((v.u >> 16) & 1u);
  return (unsigned short)(r >> 16);
}
__device__ __forceinline__ float bf2f(unsigned short x) {
  union { unsigned int u; float f; } v; v.u = ((unsigned int)x) << 16;
  return v.f;
}
__device__ __forceinline__ void g2l16(const void* g, void* l) {
  __builtin_amdgcn_global_load_lds((const __attribute__((address_space(1))) void*)g,
                                   (__attribute__((address_space(3))) void*)l, 16, 0, 0);
}

// ---------------- fused input prep ----------------
// blocks [0,8192):        x fp32 -> bf16            (4 elems/thread)
// blocks [8192,11264):    wqkv [2048,6144] -> transposed bf16 [6144,2048]
// blocks [11264,12288):   wout [2048,2048] -> transposed bf16 [2048,2048]
__global__ __launch_bounds__(256) void prep_k(const float* __restrict__ x,
                                              const float* __restrict__ wq,
                                              const float* __restrict__ wo,
                                              unsigned short* __restrict__ xb,
                                              unsigned short* __restrict__ wqT,
                                              unsigned short* __restrict__ woT) {
  __shared__ unsigned short t[64][65];
  const int b = blockIdx.x;
  if (b < 8192) {
    int i = b * 256 + threadIdx.x;
    float4 v = ((const float4*)x)[i];
    ushort4 o;
    o.x = f2bf(v.x); o.y = f2bf(v.y); o.z = f2bf(v.z); o.w = f2bf(v.w);
    ((ushort4*)xb)[i] = o;
    return;
  }
  const float* in; unsigned short* out; int C, c0, r0;
  const int R = 2048;
  if (b < 11264) { int bb = b - 8192;  in = wq; out = wqT; C = 6144; c0 = (bb % 96) * 64; r0 = (bb / 96) * 64; }
  else           { int bb = b - 11264; in = wo; out = woT; C = 2048; c0 = (bb & 31) * 64; r0 = (bb >> 5) * 64; }
  const int tx = threadIdx.x & 63, tg = threadIdx.x >> 6;
#pragma unroll
  for (int i = 0; i < 16; i++) {
    int r = i * 4 + tg;
    t[r][tx] = f2bf(in[(size_t)(r0 + r) * C + c0 + tx]);
  }
  __syncthreads();
#pragma unroll
  for (int i = 0; i < 16; i++) {
    int c = i * 4 + tg;
    out[(size_t)(c0 + c) * R + r0 + tx] = t[tx][c];
  }
}

// ---------------- GEMM: C[M,N] = A[M,K](bf16) @ BT[N,K](bf16)^T ----------------
// 128x128 tile, BK=64, XOR-swizzled conflict-free LDS (R4 structure).
// EPI=0 (qkv): fused epilogue — acc -> LDS bf16 tile, then
//   q/k: RoPE (+1/sqrt(D) scale on q) applied in-registers, coalesced store
//   v:   transposed store into vt [B,H,D,S]
// EPI=1: plain fp32 store (out projection).
template <int EPI>
__global__ __launch_bounds__(256) void gemm_bt_k(const unsigned short* __restrict__ A,
                                                 const unsigned short* __restrict__ BT,
                                                 int K, int N,
                                                 float* __restrict__ outF,
                                                 unsigned short* __restrict__ oq,
                                                 unsigned short* __restrict__ ok,
                                                 unsigned short* __restrict__ ov) {
  __shared__ __align__(16) unsigned short smem[16640];   // 33.3 KB: gemm 2x8192 | epi 128x130
  unsigned short* lA = smem;
  unsigned short* lB = smem + 8192;
  const int tid = threadIdx.x;
  const int w = tid >> 6, lane = tid & 63;
  const int quad = lane >> 4, l16 = lane & 15;
  const int m0 = blockIdx.y * 128, n0 = blockIdx.x * 128;
  const int wm = (w >> 1) * 64, wn = (w & 1) * 64;
  f32x4 acc[4][4] = {};
  const int srow = tid >> 3;                     // staging row 0..31 (+j*32)
  const int schunk = (tid & 7) ^ (srow & 7);     // swizzled logical chunk
  const unsigned short* gA = A + (size_t)(m0 + srow) * K + schunk * 8;
  const unsigned short* gB = BT + (size_t)(n0 + srow) * K + schunk * 8;
  char* ldA = (char*)lA + tid * 16;
  char* ldB = (char*)lB + tid * 16;
  const size_t rskip = (size_t)32 * K;
  for (int k0 = 0; k0 < K; k0 += 64) {
#pragma unroll
    for (int j = 0; j < 4; j++) {
      g2l16(gA + k0 + j * rskip, ldA + j * 4096);
      g2l16(gB + k0 + j * rskip, ldB + j * 4096);
    }
    __syncthreads();
#pragma unroll
    for (int ks = 0; ks < 2; ks++) {
      bf16x8 af[4], bfv[4];
#pragma unroll
      for (int i = 0; i < 4; i++)
        af[i] = *(const bf16x8*)((const char*)lA + (size_t)(wm + i * 16 + l16) * 128 +
                                 ((size_t)((ks * 4 + quad) ^ (l16 & 7)) * 16));
#pragma unroll
      for (int j = 0; j < 4; j++)
        bfv[j] = *(const bf16x8*)((const char*)lB + (size_t)(wn + j * 16 + l16) * 128 +
                                  ((size_t)((ks * 4 + quad) ^ (l16 & 7)) * 16));
#pragma unroll
      for (int i = 0; i < 4; i++)
#pragma unroll
        for (int j = 0; j < 4; j++)
          acc[i][j] = __builtin_amdgcn_mfma_f32_16x16x32_bf16(af[i], bfv[j], acc[i][j], 0, 0, 0);
    }
    __syncthreads();
  }
  if (EPI == 0) {
    const int which = n0 >> 11;          // 0=q 1=k 2=v
    const int h = (n0 >> 7) & 15;        // tile spans exactly one head
    // acc -> LDS bf16 tile [128][130]  (pad 130 keeps both write & read 2-way max)
#pragma unroll
    for (int i = 0; i < 4; i++)
#pragma unroll
      for (int r = 0; r < 4; r++) {
        int row = wm + i * 16 + quad * 4 + r;
#pragma unroll
        for (int j = 0; j < 4; j++)
          smem[row * 130 + wn + j * 16 + l16] = f2bf(acc[i][j][r]);
      }
    __syncthreads();
    const int bi2 = m0 >> 11, s0 = m0 & 2047;   // whole tile is one batch (128 | 2048)
    if (which < 2) {
      unsigned short* dst = (which == 0) ? oq : ok;
      const float scale = (which == 0) ? 0.08838834764831845f : 1.0f;
      const int d = tid & 63, tg = tid >> 6;
      const float fr = exp2f(-(float)d * (13.287712379549449f / 64.0f));
      const size_t hb = ((size_t)(bi2 * 16 + h) * 2048 + s0) * 128;
#pragma unroll
      for (int i = 0; i < 32; i++) {
        int r = i * 4 + tg;
        float a = bf2f(smem[r * 130 + d]);
        float bb = bf2f(smem[r * 130 + 64 + d]);
        float sn, cs;
        __sincosf((float)(s0 + r) * fr, &sn, &cs);
        dst[hb + (size_t)r * 128 + d]      = f2bf((a * cs - bb * sn) * scale);
        dst[hb + (size_t)r * 128 + 64 + d] = f2bf((bb * cs + a * sn) * scale);
      }
    } else {
      // v: transposed store -> vt[bh][d][s]
      const int d = tid >> 1, sh = (tid & 1) * 64;
      const size_t vr = ((size_t)(bi2 * 16 + h) * 128 + d) * 2048 + s0 + sh;
#pragma unroll
      for (int v = 0; v < 8; v++) {
        unsigned short tmp[8];
#pragma unroll
        for (int e = 0; e < 8; e++) tmp[e] = smem[(sh + v * 8 + e) * 130 + d];
        *(uint4*)(ov + vr + v * 8) = *(const uint4*)tmp;
      }
    }
  } else {
#pragma unroll
    for (int i = 0; i < 4; i++)
#pragma unroll
      for (int r = 0; r < 4; r++) {
        size_t rowb = (size_t)(m0 + wm + i * 16 + quad * 4 + r) * N;
#pragma unroll
        for (int j = 0; j < 4; j++)
          outF[rowb + n0 + wn + j * 16 + l16] = acc[i][j][r];
      }
  }
}

// ---------------- flash attention v3: register-prefetch pipelined ----------------
// Block = 128 q-rows (4 waves x 32). K/V 64-wide tiles; per iter: commit
// prefetched regs->LDS, sync, issue next tile's buffer_loads (latency overlaps
// compute), compute, sync.  No-max softmax, single l-reduce at end.
// q,k: [B*H, S, 128] bf16 (q pre-scaled); vt: [B*H, 128, S] bf16.
__global__ __launch_bounds__(256, 2) void attn_k(const unsigned short* __restrict__ qb,
                                                 const unsigned short* __restrict__ kb,
                                                 const unsigned short* __restrict__ vt,
                                                 unsigned short* __restrict__ ob) {
  __shared__ __align__(16) unsigned short lK[64 * 128];   // chunk l = row*16 + (cg^row&15)
  __shared__ __align__(16) unsigned short lV[128 * 64];   // chunk l = d*8 + (sg^d&7)
  __shared__ __align__(16) __bf16 pbuf[4][32 * 72];       // wave-private P (stride 72)
  const int tid = threadIdx.x;
  const int w = tid >> 6, lane = tid & 63;
  const int quad = lane >> 4, l16 = lane & 15;
  // complementary qt pairing for causal load balance
  const int qt = (blockIdx.y < 16) ? (int)blockIdx.x : 15 - (int)blockIdx.x;
  const int bh = blockIdx.y;
  const int bi = bh >> 4, h = bh & 15;
  const int q0w = qt * 128 + w * 32;
  const unsigned short* qp = qb + (size_t)bh * 2048 * 128;
  const unsigned short* kp = kb + (size_t)bh * 2048 * 128;
  const unsigned short* vp = vt + (size_t)bh * 128 * 2048;
  __bf16* pw = pbuf[w];

  // Q fragments: 2 row-groups x 4 k-chunks, A-layout
  bf16x8 qf[2][4];
#pragma unroll
  for (int rg = 0; rg < 2; rg++) {
    const unsigned short* qr = qp + (size_t)(q0w + rg * 16 + l16) * 128 + quad * 8;
#pragma unroll
    for (int st = 0; st < 4; st++) qf[rg][st] = *(const bf16x8*)(qr + st * 32);
  }
  f32x4 o[2][8] = {};
  f32x4 lsum[2] = {};

  // staging index precompute (chunk l = j*256 + tid)
  const int krow = tid >> 4;                       // + j*16
  const int kcg = (tid & 15) ^ krow;               // row&15 == krow (krow<16)
  const int vd = tid >> 3;                         // + j*32
  const int vsg = (tid & 7) ^ ((tid >> 3) & 7);
  unsigned short* lKdst = lK + (size_t)tid * 8;    // + j*2048 shorts
  unsigned short* lVdst = lV + (size_t)tid * 8;

  const int nkt = 2 * qt + 2;                      // block-uniform (barriers)
  const int myNkt = (q0w + 31) / 64 + 1;           // this wave's causal bound

  uint4 pk[4], pv[4];                              // register prefetch
#pragma unroll
  for (int j = 0; j < 4; j++) {
    pk[j] = *(const uint4*)(kp + (size_t)(j * 16 + krow) * 128 + kcg * 8);
    pv[j] = *(const uint4*)(vp + (size_t)(j * 32 + vd) * 2048 + vsg * 8);
  }
  for (int kt = 0; kt < nkt; kt++) {
    const int kt0 = kt * 64;
    // commit prefetched tile to LDS
#pragma unroll
    for (int j = 0; j < 4; j++) {
      *(uint4*)(lKdst + j * 2048) = pk[j];
      *(uint4*)(lVdst + j * 2048) = pv[j];
    }
    __syncthreads();
    if (kt + 1 < nkt) {  // issue next tile's loads; latency hides under compute
      const int kn = kt0 + 64;
#pragma unroll
      for (int j = 0; j < 4; j++) {
        pk[j] = *(const uint4*)(kp + (size_t)(kn + j * 16 + krow) * 128 + kcg * 8);
        pv[j] = *(const uint4*)(vp + (size_t)(j * 32 + vd) * 2048 + kn + vsg * 8);
      }
    }
    if (kt < myNkt) {
      // S = Q K^T (pre-scaled): 32 q-rows x 64 k-cols
      f32x4 sc[2][4] = {};
#pragma unroll
      for (int ct = 0; ct < 4; ct++) {
        const int nrow = ct * 16 + l16;
#pragma unroll
        for (int st = 0; st < 4; st++) {
          bf16x8 kf = *(const bf16x8*)(lK + ((size_t)nrow * 16 + ((st * 4 + quad) ^ l16)) * 8);
          sc[0][ct] = __builtin_amdgcn_mfma_f32_16x16x32_bf16(qf[0][st], kf, sc[0][ct], 0, 0, 0);
          sc[1][ct] = __builtin_amdgcn_mfma_f32_16x16x32_bf16(qf[1][st], kf, sc[1][ct], 0, 0, 0);
        }
      }
      // exp (no max-subtract); causal mask only on the wave's LAST tile
      const bool needmask = (kt == myNkt - 1);
#pragma unroll
      for (int rg = 0; rg < 2; rg++)
#pragma unroll
        for (int ct = 0; ct < 4; ct++) {
          const int col = kt0 + ct * 16 + l16;
          const int rowb = q0w + rg * 16 + quad * 4;
#pragma unroll
          for (int r = 0; r < 4; r++) {
            float s = sc[rg][ct][r];
            if (needmask && col > rowb + r) s = -1e30f;
            float e = __expf(s);
            lsum[rg][r] += e;
            pw[(rg * 16 + quad * 4 + r) * 72 + ct * 16 + l16] = (__bf16)e;
          }
        }
      // P: C-layout -> LDS -> A-layout fragments
      bf16x8 pf[2][2];
#pragma unroll
      for (int rg = 0; rg < 2; rg++)
#pragma unroll
        for (int sb = 0; sb < 2; sb++)
          pf[rg][sb] = *(const bf16x8*)(pw + (rg * 16 + l16) * 72 + sb * 32 + quad * 8);
      // O += P @ V
#pragma unroll
      for (int dt = 0; dt < 8; dt++) {
#pragma unroll
        for (int sb = 0; sb < 2; sb++) {
          bf16x8 vf = *(const bf16x8*)(lV +
              ((size_t)(dt * 16 + l16) * 8 + ((sb * 4 + quad) ^ (l16 & 7))) * 8);
          o[0][dt] = __builtin_amdgcn_mfma_f32_16x16x32_bf16(pf[0][sb], vf, o[0][dt], 0, 0, 0);
          o[1][dt] = __builtin_amdgcn_mfma_f32_16x16x32_bf16(pf[1][sb], vf, o[1][dt], 0, 0, 0);
        }
      }
    }
    __syncthreads();
  }
  // reduce l across the 16 col-lanes (once per wave)
#pragma unroll
  for (int m = 1; m < 16; m <<= 1)
#pragma unroll
    for (int rg = 0; rg < 2; rg++)
#pragma unroll
      for (int r = 0; r < 4; r++)
        lsum[rg][r] += __shfl_xor(lsum[rg][r], m, 64);
  float inv[2][4];
#pragma unroll
  for (int rg = 0; rg < 2; rg++)
#pragma unroll
    for (int r = 0; r < 4; r++) inv[rg][r] = 1.0f / lsum[rg][r];
#pragma unroll
  for (int rg = 0; rg < 2; rg++)
#pragma unroll
    for (int dt = 0; dt < 8; dt++)
#pragma unroll
      for (int r = 0; r < 4; r++)
        ob[(size_t)(bi * 2048 + q0w + rg * 16 + quad * 4 + r) * 2048 + h * 128 + dt * 16 + l16] =
            f2bf(o[rg][dt][r] * inv[rg][r]);
}

extern "C" void kernel_launch(void* const* d_in, const int* in_sizes, int n_in,
                              void* d_out, int out_size, void* d_ws, size_t ws_size,
                              hipStream_t stream) {
  const float* x = (const float*)d_in[0];
  const float* wqkv = (const float*)d_in[1];
  const float* wout = (const float*)d_in[2];
  // d_in[3] = mask, unused (causal analytically)
  char* ws = (char*)d_ws;
  const size_t MiB = 1ull << 20;
  unsigned short* xb    = (unsigned short*)(ws + 0);         // [4096,2048] bf16   16 MiB
  unsigned short* wqkvT = (unsigned short*)(ws + 16 * MiB);  // [6144,2048] bf16   24 MiB
  unsigned short* woutT = (unsigned short*)(ws + 40 * MiB);  // [2048,2048] bf16    8 MiB
  unsigned short* qb    = (unsigned short*)(ws + 48 * MiB);  // [32,2048,128] bf16 16 MiB
  unsigned short* kb    = (unsigned short*)(ws + 64 * MiB);  // [32,2048,128]      16 MiB
  unsigned short* vtb   = (unsigned short*)(ws + 80 * MiB);  // [32,128,2048]      16 MiB
  unsigned short* attnb = (unsigned short*)(ws + 96 * MiB);  // [4096,2048] bf16   16 MiB
  float* outF = (float*)d_out;

  prep_k<<<12288, 256, 0, stream>>>(x, wqkv, wout, xb, wqkvT, woutT);
  gemm_bt_k<0><<<dim3(48, 32), 256, 0, stream>>>(xb, wqkvT, 2048, 6144, nullptr, qb, kb, vtb);
  attn_k<<<dim3(16, 32), 256, 0, stream>>>(qb, kb, vtb, attnb);
  gemm_bt_k<1><<<dim3(16, 32), 256, 0, stream>>>(attnb, woutT, 2048, 2048, outF,
                                                 nullptr, nullptr, nullptr);
}

// Round 6
// 377.418 us; speedup vs baseline: 1.1618x; 1.1618x over previous
//
#include <hip/hip_runtime.h>

typedef __attribute__((ext_vector_type(8))) __bf16 bf16x8;
typedef __attribute__((ext_vector_type(4))) float f32x4;

__device__ __forceinline__ unsigned short f2bf(float x) {
  union { float f; unsigned int u; } v; v.f = x;
  unsigned int r = v.u + 0x7fffu + ((v.u >> 16) & 1u);
  return (unsigned short)(r >> 16);
}
__device__ __forceinline__ float bf2f(unsigned short x) {
  union { unsigned int u; float f; } v; v.u = ((unsigned int)x) << 16;
  return v.f;
}
__device__ __forceinline__ void g2l16(const void* g, void* l) {
  __builtin_amdgcn_global_load_lds((const __attribute__((address_space(1))) void*)g,
                                   (__attribute__((address_space(3))) void*)l, 16, 0, 0);
}

// ---------------- fused input prep ----------------
// blocks [0,8192):        x fp32 -> bf16            (4 elems/thread)
// blocks [8192,11264):    wqkv [2048,6144] -> transposed bf16 [6144,2048]
// blocks [11264,12288):   wout [2048,2048] -> transposed bf16 [2048,2048]
__global__ __launch_bounds__(256) void prep_k(const float* __restrict__ x,
                                              const float* __restrict__ wq,
                                              const float* __restrict__ wo,
                                              unsigned short* __restrict__ xb,
                                              unsigned short* __restrict__ wqT,
                                              unsigned short* __restrict__ woT) {
  __shared__ unsigned short t[64][65];
  const int b = blockIdx.x;
  if (b < 8192) {
    int i = b * 256 + threadIdx.x;
    float4 v = ((const float4*)x)[i];
    ushort4 o;
    o.x = f2bf(v.x); o.y = f2bf(v.y); o.z = f2bf(v.z); o.w = f2bf(v.w);
    ((ushort4*)xb)[i] = o;
    return;
  }
  const float* in; unsigned short* out; int C, c0, r0;
  const int R = 2048;
  if (b < 11264) { int bb = b - 8192;  in = wq; out = wqT; C = 6144; c0 = (bb % 96) * 64; r0 = (bb / 96) * 64; }
  else           { int bb = b - 11264; in = wo; out = woT; C = 2048; c0 = (bb & 31) * 64; r0 = (bb >> 5) * 64; }
  const int tx = threadIdx.x & 63, tg = threadIdx.x >> 6;
#pragma unroll
  for (int i = 0; i < 16; i++) {
    int r = i * 4 + tg;
    t[r][tx] = f2bf(in[(size_t)(r0 + r) * C + c0 + tx]);
  }
  __syncthreads();
#pragma unroll
  for (int i = 0; i < 16; i++) {
    int c = i * 4 + tg;
    out[(size_t)(c0 + c) * R + r0 + tx] = t[tx][c];
  }
}

// ---------------- GEMM: C[M,N] = A[M,K](bf16) @ BT[N,K](bf16)^T ----------------
// 128x128 tile, BK=64, XOR-swizzled conflict-free LDS (R4 structure).
// EPI=0 (qkv): fused epilogue — q/k: RoPE via [row][col] LDS tile (stride 130);
//   v: acc -> TRANSPOSED LDS tile [d][s] (stride 136, 16B-aligned rows) then
//   coalesced 16B stores into vt [B,H,D,S]  (fixes R5's 4KB-stride scatter).
// EPI=1: plain fp32 store (out projection).
template <int EPI>
__global__ __launch_bounds__(256) void gemm_bt_k(const unsigned short* __restrict__ A,
                                                 const unsigned short* __restrict__ BT,
                                                 int K, int N,
                                                 float* __restrict__ outF,
                                                 unsigned short* __restrict__ oq,
                                                 unsigned short* __restrict__ ok,
                                                 unsigned short* __restrict__ ov) {
  __shared__ __align__(16) unsigned short smem[17408];   // gemm 2x8192 | epi 128x130 or 128x136
  unsigned short* lA = smem;
  unsigned short* lB = smem + 8192;
  const int tid = threadIdx.x;
  const int w = tid >> 6, lane = tid & 63;
  const int quad = lane >> 4, l16 = lane & 15;
  const int m0 = blockIdx.y * 128, n0 = blockIdx.x * 128;
  const int wm = (w >> 1) * 64, wn = (w & 1) * 64;
  f32x4 acc[4][4] = {};
  const int srow = tid >> 3;                     // staging row 0..31 (+j*32)
  const int schunk = (tid & 7) ^ (srow & 7);     // swizzled logical chunk
  const unsigned short* gA = A + (size_t)(m0 + srow) * K + schunk * 8;
  const unsigned short* gB = BT + (size_t)(n0 + srow) * K + schunk * 8;
  char* ldA = (char*)lA + tid * 16;
  char* ldB = (char*)lB + tid * 16;
  const size_t rskip = (size_t)32 * K;
  for (int k0 = 0; k0 < K; k0 += 64) {
#pragma unroll
    for (int j = 0; j < 4; j++) {
      g2l16(gA + k0 + j * rskip, ldA + j * 4096);
      g2l16(gB + k0 + j * rskip, ldB + j * 4096);
    }
    __syncthreads();
#pragma unroll
    for (int ks = 0; ks < 2; ks++) {
      bf16x8 af[4], bfv[4];
#pragma unroll
      for (int i = 0; i < 4; i++)
        af[i] = *(const bf16x8*)((const char*)lA + (size_t)(wm + i * 16 + l16) * 128 +
                                 ((size_t)((ks * 4 + quad) ^ (l16 & 7)) * 16));
#pragma unroll
      for (int j = 0; j < 4; j++)
        bfv[j] = *(const bf16x8*)((const char*)lB + (size_t)(wn + j * 16 + l16) * 128 +
                                  ((size_t)((ks * 4 + quad) ^ (l16 & 7)) * 16));
#pragma unroll
      for (int i = 0; i < 4; i++)
#pragma unroll
        for (int j = 0; j < 4; j++)
          acc[i][j] = __builtin_amdgcn_mfma_f32_16x16x32_bf16(af[i], bfv[j], acc[i][j], 0, 0, 0);
    }
    __syncthreads();
  }
  if (EPI == 0) {
    const int which = n0 >> 11;          // 0=q 1=k 2=v
    const int h = (n0 >> 7) & 15;        // tile spans exactly one head
    const int bi2 = m0 >> 11, s0 = m0 & 2047;   // whole tile is one batch (128 | 2048)
    if (which < 2) {
      // acc -> LDS bf16 tile [row=s][col=d], stride 130
#pragma unroll
      for (int i = 0; i < 4; i++)
#pragma unroll
        for (int r = 0; r < 4; r++) {
          int row = wm + i * 16 + quad * 4 + r;
#pragma unroll
          for (int j = 0; j < 4; j++)
            smem[row * 130 + wn + j * 16 + l16] = f2bf(acc[i][j][r]);
        }
      __syncthreads();
      unsigned short* dst = (which == 0) ? oq : ok;
      const float scale = (which == 0) ? 0.08838834764831845f : 1.0f;
      const int d = tid & 63, tg = tid >> 6;
      const float fr = exp2f(-(float)d * (13.287712379549449f / 64.0f));
      const size_t hb = ((size_t)(bi2 * 16 + h) * 2048 + s0) * 128;
#pragma unroll
      for (int i = 0; i < 32; i++) {
        int r = i * 4 + tg;
        float a = bf2f(smem[r * 130 + d]);
        float bb = bf2f(smem[r * 130 + 64 + d]);
        float sn, cs;
        __sincosf((float)(s0 + r) * fr, &sn, &cs);
        dst[hb + (size_t)r * 128 + d]      = f2bf((a * cs - bb * sn) * scale);
        dst[hb + (size_t)r * 128 + 64 + d] = f2bf((bb * cs + a * sn) * scale);
      }
    } else {
      // v: acc -> transposed LDS tile [col=d][row=s], stride 136 (16B-aligned rows)
#pragma unroll
      for (int i = 0; i < 4; i++)
#pragma unroll
        for (int j = 0; j < 4; j++) {
          int row = wm + i * 16 + quad * 4;       // s base (r=0..3 consecutive)
          int col = wn + j * 16 + l16;            // d
          ushort4 t4;
          t4.x = f2bf(acc[i][j][0]); t4.y = f2bf(acc[i][j][1]);
          t4.z = f2bf(acc[i][j][2]); t4.w = f2bf(acc[i][j][3]);
          *(ushort4*)&smem[col * 136 + row] = t4; // 8B-aligned ds_write_b64
        }
      __syncthreads();
      const int sc = tid & 15, dbase = tid >> 4;
      const size_t vrb = ((size_t)(bi2 * 16 + h) * 128) * 2048 + s0;
#pragma unroll
      for (int v = 0; v < 8; v++) {
        int d = dbase + v * 16;
        uint4 val = *(const uint4*)&smem[d * 136 + sc * 8];   // 16B-aligned b128
        *(uint4*)(ov + vrb + (size_t)d * 2048 + sc * 8) = val; // 256B/quarter-wave
      }
    }
  } else {
#pragma unroll
    for (int i = 0; i < 4; i++)
#pragma unroll
      for (int r = 0; r < 4; r++) {
        size_t rowb = (size_t)(m0 + wm + i * 16 + quad * 4 + r) * N;
#pragma unroll
        for (int j = 0; j < 4; j++)
          outF[rowb + n0 + wn + j * 16 + l16] = acc[i][j][r];
      }
  }
}

// ---------------- flash attention (R4 structure, g2l16-staged) ----------------
// Block = 128 q-rows (4 waves x 32). K/V 64-wide tiles staged via
// global_load_lds (XOR-swizzled 16B chunks). No-max softmax, single l-reduce.
// q,k: [B*H, S, 128] bf16 (q pre-scaled); vt: [B*H, 128, S] bf16.
__global__ __launch_bounds__(256, 2) void attn_k(const unsigned short* __restrict__ qb,
                                                 const unsigned short* __restrict__ kb,
                                                 const unsigned short* __restrict__ vt,
                                                 unsigned short* __restrict__ ob) {
  __shared__ __align__(16) unsigned short lK[64 * 128];   // chunk l = row*16 + (cg^row&15)
  __shared__ __align__(16) unsigned short lV[128 * 64];   // chunk l = d*8 + (sg^d&7)
  __shared__ __align__(16) __bf16 pbuf[4][32 * 72];       // wave-private P (stride 72)
  const int tid = threadIdx.x;
  const int w = tid >> 6, lane = tid & 63;
  const int quad = lane >> 4, l16 = lane & 15;
  // complementary qt pairing for causal load balance
  const int qt = (blockIdx.y < 16) ? (int)blockIdx.x : 15 - (int)blockIdx.x;
  const int bh = blockIdx.y;
  const int bi = bh >> 4, h = bh & 15;
  const int q0w = qt * 128 + w * 32;
  const unsigned short* qp = qb + (size_t)bh * 2048 * 128;
  const unsigned short* kp = kb + (size_t)bh * 2048 * 128;
  const unsigned short* vp = vt + (size_t)bh * 128 * 2048;
  __bf16* pw = pbuf[w];

  // Q fragments: 2 row-groups x 4 k-chunks, A-layout
  bf16x8 qf[2][4];
#pragma unroll
  for (int rg = 0; rg < 2; rg++) {
    const unsigned short* qr = qp + (size_t)(q0w + rg * 16 + l16) * 128 + quad * 8;
#pragma unroll
    for (int st = 0; st < 4; st++) qf[rg][st] = *(const bf16x8*)(qr + st * 32);
  }
  f32x4 o[2][8] = {};
  f32x4 lsum[2] = {};

  // staging index precompute (chunk l = j*256 + tid)
  const int krow = tid >> 4;                       // + j*16
  const int kcg = (tid & 15) ^ krow;               // row&15 == krow (krow<16)
  const int vd = tid >> 3;                         // + j*32
  const int vsg = (tid & 7) ^ ((tid >> 3) & 7);
  unsigned short* lKdst = lK + (size_t)tid * 8;    // + j*2048 shorts
  unsigned short* lVdst = lV + (size_t)tid * 8;

  const int nkt = 2 * qt + 2;                      // block-uniform (barriers)
  const int myNkt = (q0w + 31) / 64 + 1;           // this wave's causal bound
  for (int kt = 0; kt < nkt; kt++) {
    const int kt0 = kt * 64;
#pragma unroll
    for (int j = 0; j < 4; j++) {
      g2l16(kp + (size_t)(kt0 + j * 16 + krow) * 128 + kcg * 8, lKdst + j * 2048);
      g2l16(vp + (size_t)(j * 32 + vd) * 2048 + kt0 + vsg * 8, lVdst + j * 2048);
    }
    __syncthreads();
    if (kt < myNkt) {
      // S = Q K^T (pre-scaled): 32 q-rows x 64 k-cols
      f32x4 sc[2][4] = {};
#pragma unroll
      for (int ct = 0; ct < 4; ct++) {
        const int nrow = ct * 16 + l16;
#pragma unroll
        for (int st = 0; st < 4; st++) {
          bf16x8 kf = *(const bf16x8*)(lK + ((size_t)nrow * 16 + ((st * 4 + quad) ^ l16)) * 8);
          sc[0][ct] = __builtin_amdgcn_mfma_f32_16x16x32_bf16(qf[0][st], kf, sc[0][ct], 0, 0, 0);
          sc[1][ct] = __builtin_amdgcn_mfma_f32_16x16x32_bf16(qf[1][st], kf, sc[1][ct], 0, 0, 0);
        }
      }
      // exp (no max-subtract); causal mask only on the wave's LAST tile
      const bool needmask = (kt == myNkt - 1);
#pragma unroll
      for (int rg = 0; rg < 2; rg++)
#pragma unroll
        for (int ct = 0; ct < 4; ct++) {
          const int col = kt0 + ct * 16 + l16;
          const int rowb = q0w + rg * 16 + quad * 4;
#pragma unroll
          for (int r = 0; r < 4; r++) {
            float s = sc[rg][ct][r];
            if (needmask && col > rowb + r) s = -1e30f;
            float e = __expf(s);
            lsum[rg][r] += e;
            pw[(rg * 16 + quad * 4 + r) * 72 + ct * 16 + l16] = (__bf16)e;
          }
        }
      // P: C-layout -> LDS -> A-layout fragments
      bf16x8 pf[2][2];
#pragma unroll
      for (int rg = 0; rg < 2; rg++)
#pragma unroll
        for (int sb = 0; sb < 2; sb++)
          pf[rg][sb] = *(const bf16x8*)(pw + (rg * 16 + l16) * 72 + sb * 32 + quad * 8);
      // O += P @ V
#pragma unroll
      for (int dt = 0; dt < 8; dt++) {
#pragma unroll
        for (int sb = 0; sb < 2; sb++) {
          bf16x8 vf = *(const bf16x8*)(lV +
              ((size_t)(dt * 16 + l16) * 8 + ((sb * 4 + quad) ^ (l16 & 7))) * 8);
          o[0][dt] = __builtin_amdgcn_mfma_f32_16x16x32_bf16(pf[0][sb], vf, o[0][dt], 0, 0, 0);
          o[1][dt] = __builtin_amdgcn_mfma_f32_16x16x32_bf16(pf[1][sb], vf, o[1][dt], 0, 0, 0);
        }
      }
    }
    __syncthreads();
  }
  // reduce l across the 16 col-lanes (once per wave)
#pragma unroll
  for (int m = 1; m < 16; m <<= 1)
#pragma unroll
    for (int rg = 0; rg < 2; rg++)
#pragma unroll
      for (int r = 0; r < 4; r++)
        lsum[rg][r] += __shfl_xor(lsum[rg][r], m, 64);
  float inv[2][4];
#pragma unroll
  for (int rg = 0; rg < 2; rg++)
#pragma unroll
    for (int r = 0; r < 4; r++) inv[rg][r] = 1.0f / lsum[rg][r];
#pragma unroll
  for (int rg = 0; rg < 2; rg++)
#pragma unroll
    for (int dt = 0; dt < 8; dt++)
#pragma unroll
      for (int r = 0; r < 4; r++)
        ob[(size_t)(bi * 2048 + q0w + rg * 16 + quad * 4 + r) * 2048 + h * 128 + dt * 16 + l16] =
            f2bf(o[rg][dt][r] * inv[rg][r]);
}

extern "C" void kernel_launch(void* const* d_in, const int* in_sizes, int n_in,
                              void* d_out, int out_size, void* d_ws, size_t ws_size,
                              hipStream_t stream) {
  const float* x = (const float*)d_in[0];
  const float* wqkv = (const float*)d_in[1];
  const float* wout = (const float*)d_in[2];
  // d_in[3] = mask, unused (causal analytically)
  char* ws = (char*)d_ws;
  const size_t MiB = 1ull << 20;
  unsigned short* xb    = (unsigned short*)(ws + 0);         // [4096,2048] bf16   16 MiB
  unsigned short* wqkvT = (unsigned short*)(ws + 16 * MiB);  // [6144,2048] bf16   24 MiB
  unsigned short* woutT = (unsigned short*)(ws + 40 * MiB);  // [2048,2048] bf16    8 MiB
  unsigned short* qb    = (unsigned short*)(ws + 48 * MiB);  // [32,2048,128] bf16 16 MiB
  unsigned short* kb    = (unsigned short*)(ws + 64 * MiB);  // [32,2048,128]      16 MiB
  unsigned short* vtb   = (unsigned short*)(ws + 80 * MiB);  // [32,128,2048]      16 MiB
  unsigned short* attnb = (unsigned short*)(ws + 96 * MiB);  // [4096,2048] bf16   16 MiB
  float* outF = (float*)d_out;

  prep_k<<<12288, 256, 0, stream>>>(x, wqkv, wout, xb, wqkvT, woutT);
  gemm_bt_k<0><<<dim3(48, 32), 256, 0, stream>>>(xb, wqkvT, 2048, 6144, nullptr, qb, kb, vtb);
  attn_k<<<dim3(16, 32), 256, 0, stream>>>(qb, kb, vtb, attnb);
  gemm_bt_k<1><<<dim3(16, 32), 256, 0, stream>>>(attnb, woutT, 2048, 2048, outF,
                                                 nullptr, nullptr, nullptr);
}